// Round 4
// baseline (233.530 us; speedup 1.0000x reference)
//
#include <hip/hip_runtime.h>
#include <cstdint>

#define BB 4
#define CDIM 128
#define HH 64
#define WW 64
#define RR 3
#define DD 7
#define DSQ 49

__device__ __forceinline__ int reflect64(int p) {
    p = (p < 0) ? -p : p;
    return (p > 63) ? (126 - p) : p;
}
__device__ __forceinline__ float sigm(float x) { return 1.0f / (1.0f + __expf(-x)); }

// ---- conv1x1(128->128) -> LN(128) -> [SiLU] -> conv1x1(128->128), one (b,h) row per block
template<bool SILU>
__global__ __launch_bounds__(512) void proj_kernel(
    const float* __restrict__ x, const float* __restrict__ w1,
    const float* __restrict__ b1, const float* __restrict__ lnw,
    const float* __restrict__ lnb, const float* __restrict__ w2,
    const float* __restrict__ b2, float* __restrict__ out)
{
    __shared__ float sX[CDIM][WW];
    __shared__ float sY[CDIM][WW];
    __shared__ float red1[8][WW];
    __shared__ float red2[8][WW];

    const int tid = threadIdx.x;
    const int w = tid & 63;
    const int q = tid >> 6;        // 0..7, wave id
    const int b = blockIdx.x >> 6;
    const int h = blockIdx.x & 63;

    const float* xrow = x + (b * CDIM * HH + h) * WW;
    for (int idx = tid; idx < CDIM * WW; idx += 512)
        sX[idx >> 6][idx & 63] = xrow[(idx >> 6) * HH * WW + (idx & 63)];
    __syncthreads();

    float acc[16];
    #pragma unroll
    for (int k = 0; k < 16; ++k) acc[k] = b1[q * 16 + k];
    for (int i = 0; i < CDIM; i += 4) {
        float x0 = sX[i][w], x1 = sX[i+1][w], x2 = sX[i+2][w], x3 = sX[i+3][w];
        #pragma unroll
        for (int k = 0; k < 16; ++k) {
            const float4 wv = *reinterpret_cast<const float4*>(&w1[(q*16+k)*CDIM + i]);
            acc[k] = fmaf(wv.x, x0, fmaf(wv.y, x1, fmaf(wv.z, x2, fmaf(wv.w, x3, acc[k]))));
        }
    }
    float s1 = 0.f, s2 = 0.f;
    #pragma unroll
    for (int k = 0; k < 16; ++k) { s1 += acc[k]; s2 += acc[k] * acc[k]; }
    red1[q][w] = s1; red2[q][w] = s2;
    __syncthreads();
    float t1 = 0.f, t2 = 0.f;
    #pragma unroll
    for (int j = 0; j < 8; ++j) { t1 += red1[j][w]; t2 += red2[j][w]; }
    const float mean = t1 * (1.0f / 128.0f);
    const float var  = t2 * (1.0f / 128.0f) - mean * mean;
    const float rstd = rsqrtf(var + 1e-6f);
    #pragma unroll
    for (int k = 0; k < 16; ++k) {
        const int o = q * 16 + k;
        float v = (acc[k] - mean) * rstd * lnw[o] + lnb[o];
        if (SILU) v = v * sigm(v);
        sY[o][w] = v;
    }
    __syncthreads();
    float acc2[16];
    #pragma unroll
    for (int k = 0; k < 16; ++k) acc2[k] = b2[q * 16 + k];
    for (int i = 0; i < CDIM; i += 4) {
        float x0 = sY[i][w], x1 = sY[i+1][w], x2 = sY[i+2][w], x3 = sY[i+3][w];
        #pragma unroll
        for (int k = 0; k < 16; ++k) {
            const float4 wv = *reinterpret_cast<const float4*>(&w2[(q*16+k)*CDIM + i]);
            acc2[k] = fmaf(wv.x, x0, fmaf(wv.y, x1, fmaf(wv.z, x2, fmaf(wv.w, x3, acc2[k]))));
        }
    }
    float* orow = out + (b * CDIM * HH + h) * WW;
    #pragma unroll
    for (int k = 0; k < 16; ++k)
        orow[(q * 16 + k) * HH * WW + w] = acc2[k];
}

// ---- sim = <patch, center>/sqrt(C); softmax over 49; * gaussian spatial kernel
__global__ __launch_bounds__(512) void simsoftmax_kernel(
    const float* __restrict__ px, const float* __restrict__ sigma_p,
    float* __restrict__ combined)
{
    __shared__ float sP[32][DD * WW];   // 32-channel chunk, 7 reflected rows
    __shared__ float sSim[DSQ][WW];

    const int tid = threadIdx.x;
    const int w = tid & 63;
    const int q = tid >> 6;
    const int b = blockIdx.x >> 6;
    const int h = blockIdx.x & 63;

    int offk[7];
    #pragma unroll
    for (int k = 0; k < 7; ++k) {
        int n = q + 8 * k; if (n > 48) n = 48;   // pad (unused lanes write sim[k] never read)
        const int ki = n / 7, kj = n % 7;
        offk[k] = ki * WW + reflect64(w + kj - RR);
    }

    float sim[7];
    #pragma unroll
    for (int k = 0; k < 7; ++k) sim[k] = 0.f;

    const float* pb = px + b * CDIM * HH * WW;
    for (int cc = 0; cc < 4; ++cc) {
        __syncthreads();
        for (int idx = tid; idx < 32 * DD * WW; idx += 512) {
            const int ww = idx & 63;
            const int rest = idx >> 6;      // 0..223
            const int ki = rest % DD;
            const int cl = rest / DD;
            const int hp = reflect64(h + ki - RR);
            sP[cl][ki * WW + ww] = pb[(cc * 32 + cl) * HH * WW + hp * WW + ww];
        }
        __syncthreads();
        for (int cl = 0; cl < 32; ++cl) {
            const float xc = sP[cl][RR * WW + w];
            #pragma unroll
            for (int k = 0; k < 7; ++k)
                sim[k] = fmaf(sP[cl][offk[k]], xc, sim[k]);
        }
    }

    const float rscale = 0.088388347648318447f;  // 1/sqrt(128)
    #pragma unroll
    for (int k = 0; k < 7; ++k) {
        const int n = q + 8 * k;
        if (n < DSQ) sSim[n][w] = sim[k] * rscale;
    }
    __syncthreads();
    float m = -1e30f;
    for (int n = 0; n < DSQ; ++n) m = fmaxf(m, sSim[n][w]);
    float ssum = 0.f;
    for (int n = 0; n < DSQ; ++n) ssum += __expf(sSim[n][w] - m);
    const float inv = 1.0f / ssum;
    const float sigma = sigma_p[0];
    const float inv2s2 = 1.0f / (2.0f * sigma * sigma);
    float* cb = combined + (b * DSQ * HH + h) * WW;
    #pragma unroll
    for (int k = 0; k < 7; ++k) {
        const int n = q + 8 * k;
        if (n < DSQ) {
            const int ki = n / 7, kj = n % 7;
            const float dx = (float)(ki - 3) * (1.0f / 3.0f);
            const float dy = (float)(kj - 3) * (1.0f / 3.0f);
            const float sk = __expf(-(dx * dx + dy * dy) * inv2s2);
            cb[n * HH * WW + w] = __expf(sim[k] * rscale - m) * inv * sk;
        }
    }
}

// ---- fixup: conv(177->49) -> LN(49) -> SiLU -> conv(49->49) -> gate -> normalize
__global__ __launch_bounds__(512) void fixup_kernel(
    const float* __restrict__ combined, const float* __restrict__ sem,
    const float* __restrict__ w1, const float* __restrict__ b1,
    const float* __restrict__ lnw, const float* __restrict__ lnb,
    const float* __restrict__ w2, const float* __restrict__ b2,
    float* __restrict__ wts)
{
    __shared__ float sCmb[DSQ][WW];
    __shared__ float sSem[CDIM][WW];
    __shared__ float sG[DSQ][WW];
    __shared__ float red1[8][WW];

    const int tid = threadIdx.x;
    const int w = tid & 63;
    const int q = tid >> 6;
    const int b = blockIdx.x >> 6;
    const int h = blockIdx.x & 63;

    const float* crow = combined + (b * DSQ * HH + h) * WW;
    for (int idx = tid; idx < DSQ * WW; idx += 512)
        sCmb[idx >> 6][idx & 63] = crow[(idx >> 6) * HH * WW + (idx & 63)];
    const float* srow = sem + (b * CDIM * HH + h) * WW;
    for (int idx = tid; idx < CDIM * WW; idx += 512)
        sSem[idx >> 6][idx & 63] = srow[(idx >> 6) * HH * WW + (idx & 63)];
    __syncthreads();

    float g[7];
    #pragma unroll
    for (int k = 0; k < 7; ++k) {
        int o = q + 8 * k; if (o > 48) o = 48;
        g[k] = b1[o];
    }
    for (int i = 0; i < DSQ; ++i) {
        const float xv = sCmb[i][w];
        #pragma unroll
        for (int k = 0; k < 7; ++k) {
            int o = q + 8 * k; if (o > 48) o = 48;
            g[k] = fmaf(w1[o * 177 + i], xv, g[k]);
        }
    }
    for (int c = 0; c < CDIM; ++c) {
        const float xv = sSem[c][w];
        #pragma unroll
        for (int k = 0; k < 7; ++k) {
            int o = q + 8 * k; if (o > 48) o = 48;
            g[k] = fmaf(w1[o * 177 + DSQ + c], xv, g[k]);
        }
    }
    float s1 = 0.f, s2 = 0.f;
    #pragma unroll
    for (int k = 0; k < 7; ++k)
        if (q + 8 * k < DSQ) { s1 += g[k]; s2 += g[k] * g[k]; }
    red1[q][w] = s1;
    __syncthreads();
    float t1 = 0.f;
    #pragma unroll
    for (int j = 0; j < 8; ++j) t1 += red1[j][w];
    __syncthreads();
    red1[q][w] = s2;
    __syncthreads();
    float t2 = 0.f;
    #pragma unroll
    for (int j = 0; j < 8; ++j) t2 += red1[j][w];
    const float mean = t1 * (1.0f / 49.0f);
    const float var  = t2 * (1.0f / 49.0f) - mean * mean;
    const float rstd = rsqrtf(var + 1e-6f);
    #pragma unroll
    for (int k = 0; k < 7; ++k) {
        const int o = q + 8 * k;
        if (o < DSQ) {
            float v = (g[k] - mean) * rstd * lnw[o] + lnb[o];
            sG[o][w] = v * sigm(v);
        }
    }
    __syncthreads();
    float f[7];
    #pragma unroll
    for (int k = 0; k < 7; ++k) {
        int o = q + 8 * k; if (o > 48) o = 48;
        f[k] = b2[o];
    }
    for (int i = 0; i < DSQ; ++i) {
        const float xv = sG[i][w];
        #pragma unroll
        for (int k = 0; k < 7; ++k) {
            int o = q + 8 * k; if (o > 48) o = 48;
            f[k] = fmaf(w2[o * DSQ + i], xv, f[k]);
        }
    }
    float c2[7];
    float ps = 0.f;
    #pragma unroll
    for (int k = 0; k < 7; ++k) {
        const int o = q + 8 * k;
        if (o < DSQ) {
            c2[k] = sCmb[o][w] * (1.0f + sigm(f[k]));
            ps += c2[k];
        } else c2[k] = 0.f;
    }
    __syncthreads();
    red1[q][w] = ps;
    __syncthreads();
    float tot = 0.f;
    #pragma unroll
    for (int j = 0; j < 8; ++j) tot += red1[j][w];
    const float invt = 1.0f / (tot + 1e-7f);
    float* wrow = wts + (b * DSQ * HH + h) * WW;
    #pragma unroll
    for (int k = 0; k < 7; ++k) {
        const int o = q + 8 * k;
        if (o < DSQ) wrow[o * HH * WW + w] = c2[k] * invt;
    }
}

// ---- out0[c] = sum_n spatial[c, nbr(n)] * wts[n]
__global__ __launch_bounds__(512) void aggregate_kernel(
    const float* __restrict__ spatial, const float* __restrict__ wts,
    float* __restrict__ out)
{
    __shared__ float sS[32][DD * WW];
    __shared__ float sWts[DSQ][WW];

    const int tid = threadIdx.x;
    const int w = tid & 63;
    const int q = tid >> 6;
    const int b = blockIdx.x >> 6;
    const int h = blockIdx.x & 63;

    const float* wrow = wts + (b * DSQ * HH + h) * WW;
    for (int idx = tid; idx < DSQ * WW; idx += 512)
        sWts[idx >> 6][idx & 63] = wrow[(idx >> 6) * HH * WW + (idx & 63)];

    const float* sb = spatial + b * CDIM * HH * WW;
    float* orow = out + (b * CDIM * HH + h) * WW;

    for (int cc = 0; cc < 4; ++cc) {
        __syncthreads();
        for (int idx = tid; idx < 32 * DD * WW; idx += 512) {
            const int ww = idx & 63;
            const int rest = idx >> 6;
            const int ki = rest % DD;
            const int cl = rest / DD;
            const int hp = reflect64(h + ki - RR);
            sS[cl][ki * WW + ww] = sb[(cc * 32 + cl) * HH * WW + hp * WW + ww];
        }
        __syncthreads();
        float acc[4] = {0.f, 0.f, 0.f, 0.f};
        for (int n = 0; n < DSQ; ++n) {
            const int ki = n / 7, kj = n % 7;
            const int off = ki * WW + reflect64(w + kj - RR);
            const float wv = sWts[n][w];
            #pragma unroll
            for (int j = 0; j < 4; ++j)
                acc[j] = fmaf(sS[q * 4 + j][off], wv, acc[j]);
        }
        #pragma unroll
        for (int j = 0; j < 4; ++j)
            orow[(cc * 32 + q * 4 + j) * HH * WW + w] = acc[j];
    }
}

extern "C" void kernel_launch(void* const* d_in, const int* in_sizes, int n_in,
                              void* d_out, int out_size, void* d_ws, size_t ws_size,
                              hipStream_t stream) {
    (void)in_sizes; (void)n_in; (void)out_size; (void)ws_size;
    const float* spatial  = (const float*)d_in[0];
    const float* semantic = (const float*)d_in[1];
    const float* rp_w1 = (const float*)d_in[2];
    const float* rp_b1 = (const float*)d_in[3];
    const float* rp_lnw = (const float*)d_in[4];
    const float* rp_lnb = (const float*)d_in[5];
    const float* rp_w2 = (const float*)d_in[6];
    const float* rp_b2 = (const float*)d_in[7];
    const float* fx_w1 = (const float*)d_in[8];
    const float* fx_b1 = (const float*)d_in[9];
    const float* fx_lnw = (const float*)d_in[10];
    const float* fx_lnb = (const float*)d_in[11];
    const float* fx_w2 = (const float*)d_in[12];
    const float* fx_b2 = (const float*)d_in[13];
    const float* sigma = (const float*)d_in[14];
    const float* op_w1 = (const float*)d_in[15];
    const float* op_b1 = (const float*)d_in[16];
    const float* op_lnw = (const float*)d_in[17];
    const float* op_lnb = (const float*)d_in[18];
    const float* op_w2 = (const float*)d_in[19];
    const float* op_b2 = (const float*)d_in[20];

    float* ws = (float*)d_ws;
    float* proj_x   = ws;                       // 2,097,152 floats
    float* combined = ws + 2097152;             //   802,816 floats
    float* wtsbuf   = ws + 2899968;             //   802,816 floats
    float* agg      = proj_x;                   // reuse (proj_x dead after simsoftmax)
    float* outp     = (float*)d_out;

    dim3 grid(BB * HH), blk(512);
    proj_kernel<true><<<grid, blk, 0, stream>>>(semantic, rp_w1, rp_b1, rp_lnw, rp_lnb,
                                                rp_w2, rp_b2, proj_x);
    simsoftmax_kernel<<<grid, blk, 0, stream>>>(proj_x, sigma, combined);
    fixup_kernel<<<grid, blk, 0, stream>>>(combined, semantic, fx_w1, fx_b1, fx_lnw,
                                           fx_lnb, fx_w2, fx_b2, wtsbuf);
    aggregate_kernel<<<grid, blk, 0, stream>>>(spatial, wtsbuf, agg);
    proj_kernel<false><<<grid, blk, 0, stream>>>(agg, op_w1, op_b1, op_lnw, op_lnb,
                                                 op_w2, op_b2, outp);
}